// Round 4
// baseline (244.848 us; speedup 1.0000x reference)
//
#include <hip/hip_runtime.h>

#define N_PTS   524288
#define P_PTS   65536
#define B_SC    8
#define SEGS    512
#define GSEG    (B_SC*SEGS)      /* 4096 */
#define HID     256

// ---------------------------------------------------------------------------
// Kernel 1: per-block partial histograms of p2s (no global atomics, no memset)
// 512 blocks x 1024 points. part[block][SEGS] written coalesced.
// ---------------------------------------------------------------------------
__global__ __launch_bounds__(256) void count_kernel(
    const int* __restrict__ p2s, int* __restrict__ part)
{
    __shared__ int lc[SEGS];
    const int t = threadIdx.x;
    lc[t] = 0; lc[t + 256] = 0;
    __syncthreads();
    const int q0 = blockIdx.x * 1024 + t * 4;
    const int4 s4 = *reinterpret_cast<const int4*>(p2s + q0);
    atomicAdd(&lc[s4.x], 1);
    atomicAdd(&lc[s4.y], 1);
    atomicAdd(&lc[s4.z], 1);
    atomicAdd(&lc[s4.w], 1);
    __syncthreads();
    part[blockIdx.x * SEGS + t]       = lc[t];
    part[blockIdx.x * SEGS + t + 256] = lc[t + 256];
}

// ---------------------------------------------------------------------------
// Kernel 2: sum partials -> per-seg counts -> exclusive scan (single block).
// Partial-sum reads are fully coalesced (512 consecutive k per 512-thread
// half); scan operates on LDS counts.
// ---------------------------------------------------------------------------
__global__ __launch_bounds__(1024) void scan_kernel(
    const int* __restrict__ part, int* __restrict__ offs, int* __restrict__ cursor)
{
    __shared__ int scnt[GSEG];     // 16 KB
    __shared__ int tmp[1024];
    const int t = threadIdx.x;
    const int k = t & 511;
    const int h = t >> 9;          // 0 or 1
    #pragma unroll
    for (int j = 0; j < 4; ++j) {
        const int scene = h + j * 2;
        const int* pp = part + (scene * 64) * SEGS + k;
        int s = 0;
        #pragma unroll 8
        for (int b = 0; b < 64; ++b) s += pp[b * SEGS];
        scnt[scene * SEGS + k] = s;
    }
    __syncthreads();

    int v[4]; int s = 0;
    #pragma unroll
    for (int i = 0; i < 4; ++i) { v[i] = scnt[t*4 + i]; s += v[i]; }
    tmp[t] = s;
    __syncthreads();
    for (int off = 1; off < 1024; off <<= 1) {
        int x = (t >= off) ? tmp[t - off] : 0;
        __syncthreads();
        tmp[t] += x;
        __syncthreads();
    }
    int excl = (t > 0) ? tmp[t-1] : 0;
    #pragma unroll
    for (int i = 0; i < 4; ++i) {
        offs[t*4 + i] = excl;
        cursor[t*4 + i] = excl;
        excl += v[i];
    }
    if (t == 1023) offs[4096] = excl;   // == N
}

// ---------------------------------------------------------------------------
// Kernel 3: fused compose + scatter. Computes the index chain (4 independent
// chains per thread) and scatters int4(p,i1,i2,i3) into segment-contiguous
// sorted[] via cursor atomics. No intermediate pk buffer.
// ---------------------------------------------------------------------------
__global__ __launch_bounds__(256) void build_kernel(
    const int* __restrict__ inv1, const int* __restrict__ inv2,
    const int* __restrict__ inv3, const int* __restrict__ p2s,
    int* __restrict__ cursor, int4* __restrict__ sorted)
{
    const int q0 = blockIdx.x * 1024 + threadIdx.x * 4;
    const int4 a4 = *reinterpret_cast<const int4*>(inv1 + q0);
    const int b0 = inv2[a4.x], b1 = inv2[a4.y], b2 = inv2[a4.z], b3 = inv2[a4.w];
    const int c0 = inv3[b0],   c1 = inv3[b1],   c2 = inv3[b2],   c3 = inv3[b3];
    const int4 s4 = *reinterpret_cast<const int4*>(p2s + q0);
    const int sbase = (q0 >> 16) * SEGS;
    const int p0 = atomicAdd(&cursor[sbase + s4.x], 1);
    const int p1 = atomicAdd(&cursor[sbase + s4.y], 1);
    const int p2 = atomicAdd(&cursor[sbase + s4.z], 1);
    const int p3 = atomicAdd(&cursor[sbase + s4.w], 1);
    sorted[p0] = make_int4(q0 + 0, a4.x, b0, c0);
    sorted[p1] = make_int4(q0 + 1, a4.y, b1, c1);
    sorted[p2] = make_int4(q0 + 2, a4.z, b2, c2);
    sorted[p3] = make_int4(q0 + 3, a4.w, b3, c3);
}

// ---------------------------------------------------------------------------
// Kernel 4 (x4 levels): per-segment mean of one level.
// Block = one (scene,seg). CL=C/4 channel-lanes, NS=256/CL point-slots,
// unroll 4 -> 4*NS points in flight. Per-level launch keeps the phase's
// gather footprint (8-32 MB) L2/L3-resident, un-polluted by other levels.
// ---------------------------------------------------------------------------
template<int C, int SEL>
__global__ __launch_bounds__(256) void reduce_level_kernel(
    const float* __restrict__ fb, const int4* __restrict__ sorted,
    const int* __restrict__ offs, float* __restrict__ mo)
{
    constexpr int CL = C / 4;        // float4 lanes per point
    constexpr int NS = 256 / CL;     // concurrent point slots
    __shared__ int    s_idx[512];
    __shared__ float4 s_red[256];

    const int g = blockIdx.x;
    const int start = offs[g], end = offs[g+1];
    const int t = threadIdx.x;
    const int slot = t / CL;
    const int coff = (t % CL) * 4;

    float ax = 0.f, ay = 0.f, az = 0.f, aw = 0.f;
    for (int cs = start; cs < end; cs += 512) {
        const int n = min(512, end - cs);
        __syncthreads();
        for (int i = t; i < n; i += 256) {
            const int4 v = sorted[cs + i];
            s_idx[i] = (SEL == 0) ? v.x : (SEL == 1) ? v.y : (SEL == 2) ? v.z : v.w;
        }
        __syncthreads();
        int k = slot;
        for (; k + 3*NS < n; k += 4*NS) {
            const int ia = s_idx[k], ib = s_idx[k + NS], ic = s_idx[k + 2*NS], id = s_idx[k + 3*NS];
            const float4 va = *reinterpret_cast<const float4*>(fb + (size_t)ia * C + coff);
            const float4 vb = *reinterpret_cast<const float4*>(fb + (size_t)ib * C + coff);
            const float4 vc = *reinterpret_cast<const float4*>(fb + (size_t)ic * C + coff);
            const float4 vd = *reinterpret_cast<const float4*>(fb + (size_t)id * C + coff);
            ax += va.x + vb.x + vc.x + vd.x;
            ay += va.y + vb.y + vc.y + vd.y;
            az += va.z + vb.z + vc.z + vd.z;
            aw += va.w + vb.w + vc.w + vd.w;
        }
        for (; k < n; k += NS) {
            const int ia = s_idx[k];
            const float4 va = *reinterpret_cast<const float4*>(fb + (size_t)ia * C + coff);
            ax += va.x; ay += va.y; az += va.z; aw += va.w;
        }
    }

    s_red[t] = make_float4(ax, ay, az, aw);
    __syncthreads();
    if (t < CL) {
        float4 s = s_red[t];
        #pragma unroll
        for (int sl = 1; sl < NS; ++sl) {
            const float4 p = s_red[sl * CL + t];
            s.x += p.x; s.y += p.y; s.z += p.z; s.w += p.w;
        }
        const float inv = 1.0f / fmaxf((float)(end - start), 1.0f);
        s.x *= inv; s.y *= inv; s.z *= inv; s.w *= inv;
        *reinterpret_cast<float4*>(mo + (size_t)g * C + t * 4) = s;
    }
}

// ---------------------------------------------------------------------------
// Kernel 5 (fused x4): [4096,C] x [C,256] GEMM + bias + LayerNorm -> out slab.
// 16 rows/block halves W re-reads vs 8 rows/block.
// ---------------------------------------------------------------------------
#define GROWS 16

template<int C>
__device__ __forceinline__ void gemm_ln_body(
    float (*sh)[HID], int row0,
    const float* __restrict__ m, const float* __restrict__ W,
    const float* __restrict__ bias, const float* __restrict__ gma,
    const float* __restrict__ bta, float* __restrict__ out)
{
    const int t = threadIdx.x;
    float acc[GROWS];
    #pragma unroll
    for (int r = 0; r < GROWS; ++r) acc[r] = 0.f;
    const float4* __restrict__ m4 = reinterpret_cast<const float4*>(m);

    for (int c4 = 0; c4 < C; c4 += 4) {
        const float w0 = W[(c4+0)*HID + t];
        const float w1 = W[(c4+1)*HID + t];
        const float w2 = W[(c4+2)*HID + t];
        const float w3 = W[(c4+3)*HID + t];
        #pragma unroll
        for (int r = 0; r < GROWS; ++r) {
            const float4 mv = m4[((row0 + r) * C + c4) >> 2];   // uniform -> s_load
            acc[r] = fmaf(mv.x, w0, acc[r]);
            acc[r] = fmaf(mv.y, w1, acc[r]);
            acc[r] = fmaf(mv.z, w2, acc[r]);
            acc[r] = fmaf(mv.w, w3, acc[r]);
        }
    }
    const float bb = bias[t];
    #pragma unroll
    for (int r = 0; r < GROWS; ++r) sh[r][t] = acc[r] + bb;
    __syncthreads();

    const int wave = t >> 6, lane = t & 63;
    for (int r = wave; r < GROWS; r += 4) {
        const float v0 = sh[r][lane      ];
        const float v1 = sh[r][lane + 64 ];
        const float v2 = sh[r][lane + 128];
        const float v3 = sh[r][lane + 192];
        float s  = v0 + v1 + v2 + v3;
        float sq = v0*v0 + v1*v1 + v2*v2 + v3*v3;
        #pragma unroll
        for (int o = 32; o > 0; o >>= 1) {
            s  += __shfl_xor(s,  o);
            sq += __shfl_xor(sq, o);
        }
        const float mean = s * (1.0f / 256.0f);
        const float var  = sq * (1.0f / 256.0f) - mean * mean;
        const float rs   = rsqrtf(var + 1e-5f);
        float* o_ = out + ((size_t)(row0 + r)) * HID;
        o_[lane      ] = (v0 - mean) * rs * gma[lane      ] + bta[lane      ];
        o_[lane + 64 ] = (v1 - mean) * rs * gma[lane + 64 ] + bta[lane + 64 ];
        o_[lane + 128] = (v2 - mean) * rs * gma[lane + 128] + bta[lane + 128];
        o_[lane + 192] = (v3 - mean) * rs * gma[lane + 192] + bta[lane + 192];
    }
}

__global__ __launch_bounds__(256) void gemm_ln_all_kernel(
    const float* __restrict__ m0, const float* __restrict__ m1,
    const float* __restrict__ m2, const float* __restrict__ m3,
    const float* __restrict__ W0, const float* __restrict__ b0,
    const float* __restrict__ g0, const float* __restrict__ bt0,
    const float* __restrict__ W1, const float* __restrict__ b1,
    const float* __restrict__ g1, const float* __restrict__ bt1,
    const float* __restrict__ W2, const float* __restrict__ b2,
    const float* __restrict__ g2, const float* __restrict__ bt2,
    const float* __restrict__ W3, const float* __restrict__ b3,
    const float* __restrict__ g3, const float* __restrict__ bt3,
    float* __restrict__ out)
{
    __shared__ float sh[GROWS][HID];
    const int blk = blockIdx.x;
    const int bpl = GSEG / GROWS;               // 256 blocks per level
    const int level = blk / bpl;
    const int row0 = (blk % bpl) * GROWS;
    const size_t slab = (size_t)GSEG * HID;
    switch (level) {
        case 0: gemm_ln_body<64 >(sh, row0, m0, W0, b0, g0, bt0, out + 3*slab); break;
        case 1: gemm_ln_body<64 >(sh, row0, m1, W1, b1, g1, bt1, out + 2*slab); break;
        case 2: gemm_ln_body<128>(sh, row0, m2, W2, b2, g2, bt2, out + 1*slab); break;
        default: gemm_ln_body<256>(sh, row0, m3, W3, b3, g3, bt3, out); break;
    }
}

// ---------------------------------------------------------------------------
extern "C" void kernel_launch(void* const* d_in, const int* in_sizes, int n_in,
                              void* d_out, int out_size, void* d_ws, size_t ws_size,
                              hipStream_t stream)
{
    const float* f0  = (const float*)d_in[0];
    const float* f1  = (const float*)d_in[1];
    const float* f2  = (const float*)d_in[2];
    const float* f3  = (const float*)d_in[3];
    const int* inv1  = (const int*)d_in[4];
    const int* inv2  = (const int*)d_in[5];
    const int* inv3  = (const int*)d_in[6];
    const int* p2s   = (const int*)d_in[7];
    const float* W0  = (const float*)d_in[8];
    const float* b0  = (const float*)d_in[9];
    const float* g0  = (const float*)d_in[10];
    const float* bt0 = (const float*)d_in[11];
    const float* W1  = (const float*)d_in[12];
    const float* b1  = (const float*)d_in[13];
    const float* g1  = (const float*)d_in[14];
    const float* bt1 = (const float*)d_in[15];
    const float* W2  = (const float*)d_in[16];
    const float* b2  = (const float*)d_in[17];
    const float* g2  = (const float*)d_in[18];
    const float* bt2 = (const float*)d_in[19];
    const float* W3  = (const float*)d_in[20];
    const float* b3  = (const float*)d_in[21];
    const float* g3  = (const float*)d_in[22];
    const float* bt3 = (const float*)d_in[23];
    float* out = (float*)d_out;

    char* ws = (char*)d_ws;
    int4*  sorted = (int4*)(ws);                           // 8 MB
    int*   part   = (int*)(ws + (8u<<20));                 // 1 MB
    int*   offs   = (int*)(ws + (9u<<20));                 // 16.4 KB
    int*   cursor = (int*)(ws + (9u<<20) + 32768);         // 16 KB
    float* m0     = (float*)(ws + (10u<<20));              // 1 MB
    float* m1     = m0 + (size_t)GSEG * 64;                // 1 MB
    float* m2     = m1 + (size_t)GSEG * 64;                // 2 MB
    float* m3     = m2 + (size_t)GSEG * 128;               // 4 MB  (total ~18 MB)

    count_kernel<<<N_PTS/1024, 256, 0, stream>>>(p2s, part);
    scan_kernel<<<1, 1024, 0, stream>>>(part, offs, cursor);
    build_kernel<<<N_PTS/1024, 256, 0, stream>>>(inv1, inv2, inv3, p2s, cursor, sorted);

    reduce_level_kernel<256,3><<<GSEG, 256, 0, stream>>>(f3, sorted, offs, m3);
    reduce_level_kernel<128,2><<<GSEG, 256, 0, stream>>>(f2, sorted, offs, m2);
    reduce_level_kernel<64, 1><<<GSEG, 256, 0, stream>>>(f1, sorted, offs, m1);
    reduce_level_kernel<64, 0><<<GSEG, 256, 0, stream>>>(f0, sorted, offs, m0);

    gemm_ln_all_kernel<<<4*GSEG/GROWS, 256, 0, stream>>>(
        m0, m1, m2, m3,
        W0, b0, g0, bt0, W1, b1, g1, bt1,
        W2, b2, g2, bt2, W3, b3, g3, bt3, out);
}

// Round 5
// 243.393 us; speedup vs baseline: 1.0060x; 1.0060x over previous
//
#include <hip/hip_runtime.h>

#define N_PTS   524288
#define P_PTS   65536
#define B_SC    8
#define SEGS    512
#define GSEG    (B_SC*SEGS)      /* 4096 */
#define HID     256
#define GROWS   16

// ---------------------------------------------------------------------------
// Kernel 1: per-block partial histograms of p2s (no global atomics, no memset)
// ---------------------------------------------------------------------------
__global__ __launch_bounds__(256) void count_kernel(
    const int* __restrict__ p2s, int* __restrict__ part)
{
    __shared__ int lc[SEGS];
    const int t = threadIdx.x;
    lc[t] = 0; lc[t + 256] = 0;
    __syncthreads();
    const int q0 = blockIdx.x * 1024 + t * 4;
    const int4 s4 = *reinterpret_cast<const int4*>(p2s + q0);
    atomicAdd(&lc[s4.x], 1);
    atomicAdd(&lc[s4.y], 1);
    atomicAdd(&lc[s4.z], 1);
    atomicAdd(&lc[s4.w], 1);
    __syncthreads();
    part[blockIdx.x * SEGS + t]       = lc[t];
    part[blockIdx.x * SEGS + t + 256] = lc[t + 256];
}

// ---------------------------------------------------------------------------
// Kernel 2: sum partials -> per-seg counts -> exclusive scan (single block)
// ---------------------------------------------------------------------------
__global__ __launch_bounds__(1024) void scan_kernel(
    const int* __restrict__ part, int* __restrict__ offs, int* __restrict__ cursor)
{
    __shared__ int scnt[GSEG];     // 16 KB
    __shared__ int tmp[1024];
    const int t = threadIdx.x;
    const int k = t & 511;
    const int h = t >> 9;          // 0 or 1
    #pragma unroll
    for (int j = 0; j < 4; ++j) {
        const int scene = h + j * 2;
        const int* pp = part + (scene * 64) * SEGS + k;
        int s = 0;
        #pragma unroll 8
        for (int b = 0; b < 64; ++b) s += pp[b * SEGS];
        scnt[scene * SEGS + k] = s;
    }
    __syncthreads();

    int v[4]; int s = 0;
    #pragma unroll
    for (int i = 0; i < 4; ++i) { v[i] = scnt[t*4 + i]; s += v[i]; }
    tmp[t] = s;
    __syncthreads();
    for (int off = 1; off < 1024; off <<= 1) {
        int x = (t >= off) ? tmp[t - off] : 0;
        __syncthreads();
        tmp[t] += x;
        __syncthreads();
    }
    int excl = (t > 0) ? tmp[t-1] : 0;
    #pragma unroll
    for (int i = 0; i < 4; ++i) {
        offs[t*4 + i] = excl;
        cursor[t*4 + i] = excl;
        excl += v[i];
    }
    if (t == 1023) offs[4096] = excl;   // == N
}

// ---------------------------------------------------------------------------
// Kernel 3: fused compose + scatter into segment-contiguous sorted[]
// ---------------------------------------------------------------------------
__global__ __launch_bounds__(256) void build_kernel(
    const int* __restrict__ inv1, const int* __restrict__ inv2,
    const int* __restrict__ inv3, const int* __restrict__ p2s,
    int* __restrict__ cursor, int4* __restrict__ sorted)
{
    const int q0 = blockIdx.x * 1024 + threadIdx.x * 4;
    const int4 a4 = *reinterpret_cast<const int4*>(inv1 + q0);
    const int b0 = inv2[a4.x], b1 = inv2[a4.y], b2 = inv2[a4.z], b3 = inv2[a4.w];
    const int c0 = inv3[b0],   c1 = inv3[b1],   c2 = inv3[b2],   c3 = inv3[b3];
    const int4 s4 = *reinterpret_cast<const int4*>(p2s + q0);
    const int sbase = (q0 >> 16) * SEGS;
    const int p0 = atomicAdd(&cursor[sbase + s4.x], 1);
    const int p1 = atomicAdd(&cursor[sbase + s4.y], 1);
    const int p2 = atomicAdd(&cursor[sbase + s4.z], 1);
    const int p3 = atomicAdd(&cursor[sbase + s4.w], 1);
    sorted[p0] = make_int4(q0 + 0, a4.x, b0, c0);
    sorted[p1] = make_int4(q0 + 1, a4.y, b1, c1);
    sorted[p2] = make_int4(q0 + 2, a4.z, b2, c2);
    sorted[p3] = make_int4(q0 + 3, a4.w, b3, c3);
}

// ---------------------------------------------------------------------------
// Kernel 4 (x4 levels): per-segment mean of one level.
// CL=C/4 channel-lanes, NS=256/CL point-slots, unroll 8 -> 8 independent
// float4 gathers in flight per lane.
// ---------------------------------------------------------------------------
template<int C, int SEL>
__global__ __launch_bounds__(256) void reduce_level_kernel(
    const float* __restrict__ fb, const int4* __restrict__ sorted,
    const int* __restrict__ offs, float* __restrict__ mo)
{
    constexpr int CL = C / 4;        // float4 lanes per point
    constexpr int NS = 256 / CL;     // concurrent point slots
    __shared__ int    s_idx[512];
    __shared__ float4 s_red[256];

    const int g = blockIdx.x;
    const int start = offs[g], end = offs[g+1];
    const int t = threadIdx.x;
    const int slot = t / CL;
    const int coff = (t % CL) * 4;

    float ax = 0.f, ay = 0.f, az = 0.f, aw = 0.f;
    for (int cs = start; cs < end; cs += 512) {
        const int n = min(512, end - cs);
        __syncthreads();
        for (int i = t; i < n; i += 256) {
            const int4 v = sorted[cs + i];
            s_idx[i] = (SEL == 0) ? v.x : (SEL == 1) ? v.y : (SEL == 2) ? v.z : v.w;
        }
        __syncthreads();
        int k = slot;
        for (; k + 7*NS < n; k += 8*NS) {
            float4 v[8];
            #pragma unroll
            for (int u = 0; u < 8; ++u) {
                const int ia = s_idx[k + u*NS];
                v[u] = *reinterpret_cast<const float4*>(fb + (size_t)ia * C + coff);
            }
            #pragma unroll
            for (int u = 0; u < 8; ++u) {
                ax += v[u].x; ay += v[u].y; az += v[u].z; aw += v[u].w;
            }
        }
        for (; k < n; k += NS) {
            const int ia = s_idx[k];
            const float4 va = *reinterpret_cast<const float4*>(fb + (size_t)ia * C + coff);
            ax += va.x; ay += va.y; az += va.z; aw += va.w;
        }
    }

    s_red[t] = make_float4(ax, ay, az, aw);
    __syncthreads();
    if (t < CL) {
        float4 s = s_red[t];
        #pragma unroll
        for (int sl = 1; sl < NS; ++sl) {
            const float4 p = s_red[sl * CL + t];
            s.x += p.x; s.y += p.y; s.z += p.z; s.w += p.w;
        }
        const float inv = 1.0f / fmaxf((float)(end - start), 1.0f);
        s.x *= inv; s.y *= inv; s.z *= inv; s.w *= inv;
        *reinterpret_cast<float4*>(mo + (size_t)g * C + t * 4) = s;
    }
}

// ---------------------------------------------------------------------------
// Kernel 5 (fused x4): [4096,C] x [C,256] GEMM + bias + LayerNorm.
// m-tile staged in LDS (float4 broadcast reads); W loads software-pipelined.
// ---------------------------------------------------------------------------
template<int C>
__device__ __forceinline__ void gemm_ln_body(
    float* smem, int row0,
    const float* __restrict__ m, const float* __restrict__ W,
    const float* __restrict__ bias, const float* __restrict__ gma,
    const float* __restrict__ bta, float* __restrict__ out)
{
    const int t = threadIdx.x;

    // stage m tile [GROWS][C] into LDS, coalesced float4
    float4* sm4 = reinterpret_cast<float4*>(smem);
    const float4* gm4 = reinterpret_cast<const float4*>(m + (size_t)row0 * C);
    constexpr int NV = GROWS * C / 4;
    #pragma unroll
    for (int i = t; i < NV; i += 256) sm4[i] = gm4[i];
    __syncthreads();

    float acc[GROWS];
    #pragma unroll
    for (int r = 0; r < GROWS; ++r) acc[r] = 0.f;

    // software-pipelined W loads: prefetch next 4 rows while computing current
    float w0 = W[t], w1 = W[HID + t], w2 = W[2*HID + t], w3 = W[3*HID + t];
    for (int c4 = 0; ; c4 += 4) {
        const bool last = (c4 + 4 >= C);
        float n0 = 0.f, n1 = 0.f, n2 = 0.f, n3 = 0.f;
        if (!last) {
            const float* Wn = W + (c4 + 4) * HID + t;
            n0 = Wn[0]; n1 = Wn[HID]; n2 = Wn[2*HID]; n3 = Wn[3*HID];
        }
        #pragma unroll
        for (int r = 0; r < GROWS; ++r) {
            const float4 mv = sm4[(r * C + c4) >> 2];   // LDS broadcast
            acc[r] = fmaf(mv.x, w0, acc[r]);
            acc[r] = fmaf(mv.y, w1, acc[r]);
            acc[r] = fmaf(mv.z, w2, acc[r]);
            acc[r] = fmaf(mv.w, w3, acc[r]);
        }
        if (last) break;
        w0 = n0; w1 = n1; w2 = n2; w3 = n3;
    }

    __syncthreads();                 // m-tile no longer needed; reuse as sh
    const float bb = bias[t];
    #pragma unroll
    for (int r = 0; r < GROWS; ++r) smem[r * HID + t] = acc[r] + bb;
    __syncthreads();

    const int wave = t >> 6, lane = t & 63;
    for (int r = wave; r < GROWS; r += 4) {
        const float* sh = smem + r * HID;
        const float v0 = sh[lane      ];
        const float v1 = sh[lane + 64 ];
        const float v2 = sh[lane + 128];
        const float v3 = sh[lane + 192];
        float s  = v0 + v1 + v2 + v3;
        float sq = v0*v0 + v1*v1 + v2*v2 + v3*v3;
        #pragma unroll
        for (int o = 32; o > 0; o >>= 1) {
            s  += __shfl_xor(s,  o);
            sq += __shfl_xor(sq, o);
        }
        const float mean = s * (1.0f / 256.0f);
        const float var  = sq * (1.0f / 256.0f) - mean * mean;
        const float rs   = rsqrtf(var + 1e-5f);
        float* o_ = out + ((size_t)(row0 + r)) * HID;
        o_[lane      ] = (v0 - mean) * rs * gma[lane      ] + bta[lane      ];
        o_[lane + 64 ] = (v1 - mean) * rs * gma[lane + 64 ] + bta[lane + 64 ];
        o_[lane + 128] = (v2 - mean) * rs * gma[lane + 128] + bta[lane + 128];
        o_[lane + 192] = (v3 - mean) * rs * gma[lane + 192] + bta[lane + 192];
    }
}

__global__ __launch_bounds__(256) void gemm_ln_all_kernel(
    const float* __restrict__ m0, const float* __restrict__ m1,
    const float* __restrict__ m2, const float* __restrict__ m3,
    const float* __restrict__ W0, const float* __restrict__ b0,
    const float* __restrict__ g0, const float* __restrict__ bt0,
    const float* __restrict__ W1, const float* __restrict__ b1,
    const float* __restrict__ g1, const float* __restrict__ bt1,
    const float* __restrict__ W2, const float* __restrict__ b2,
    const float* __restrict__ g2, const float* __restrict__ bt2,
    const float* __restrict__ W3, const float* __restrict__ b3,
    const float* __restrict__ g3, const float* __restrict__ bt3,
    float* __restrict__ out)
{
    __shared__ float smem[GROWS * HID];         // 16 KB, reused m-tile -> LN
    const int blk = blockIdx.x;
    const int level = blk & 3;                  // interleave levels across CUs
    const int row0 = (blk >> 2) * GROWS;
    const size_t slab = (size_t)GSEG * HID;
    switch (level) {
        case 0: gemm_ln_body<64 >(smem, row0, m0, W0, b0, g0, bt0, out + 3*slab); break;
        case 1: gemm_ln_body<64 >(smem, row0, m1, W1, b1, g1, bt1, out + 2*slab); break;
        case 2: gemm_ln_body<128>(smem, row0, m2, W2, b2, g2, bt2, out + 1*slab); break;
        default: gemm_ln_body<256>(smem, row0, m3, W3, b3, g3, bt3, out); break;
    }
}

// ---------------------------------------------------------------------------
extern "C" void kernel_launch(void* const* d_in, const int* in_sizes, int n_in,
                              void* d_out, int out_size, void* d_ws, size_t ws_size,
                              hipStream_t stream)
{
    const float* f0  = (const float*)d_in[0];
    const float* f1  = (const float*)d_in[1];
    const float* f2  = (const float*)d_in[2];
    const float* f3  = (const float*)d_in[3];
    const int* inv1  = (const int*)d_in[4];
    const int* inv2  = (const int*)d_in[5];
    const int* inv3  = (const int*)d_in[6];
    const int* p2s   = (const int*)d_in[7];
    const float* W0  = (const float*)d_in[8];
    const float* b0  = (const float*)d_in[9];
    const float* g0  = (const float*)d_in[10];
    const float* bt0 = (const float*)d_in[11];
    const float* W1  = (const float*)d_in[12];
    const float* b1  = (const float*)d_in[13];
    const float* g1  = (const float*)d_in[14];
    const float* bt1 = (const float*)d_in[15];
    const float* W2  = (const float*)d_in[16];
    const float* b2  = (const float*)d_in[17];
    const float* g2  = (const float*)d_in[18];
    const float* bt2 = (const float*)d_in[19];
    const float* W3  = (const float*)d_in[20];
    const float* b3  = (const float*)d_in[21];
    const float* g3  = (const float*)d_in[22];
    const float* bt3 = (const float*)d_in[23];
    float* out = (float*)d_out;

    char* ws = (char*)d_ws;
    int4*  sorted = (int4*)(ws);                           // 8 MB
    int*   part   = (int*)(ws + (8u<<20));                 // 1 MB
    int*   offs   = (int*)(ws + (9u<<20));                 // 16.4 KB
    int*   cursor = (int*)(ws + (9u<<20) + 32768);         // 16 KB
    float* m0     = (float*)(ws + (10u<<20));              // 1 MB
    float* m1     = m0 + (size_t)GSEG * 64;                // 1 MB
    float* m2     = m1 + (size_t)GSEG * 64;                // 2 MB
    float* m3     = m2 + (size_t)GSEG * 128;               // 4 MB  (total ~18 MB)

    count_kernel<<<N_PTS/1024, 256, 0, stream>>>(p2s, part);
    scan_kernel<<<1, 1024, 0, stream>>>(part, offs, cursor);
    build_kernel<<<N_PTS/1024, 256, 0, stream>>>(inv1, inv2, inv3, p2s, cursor, sorted);

    reduce_level_kernel<256,3><<<GSEG, 256, 0, stream>>>(f3, sorted, offs, m3);
    reduce_level_kernel<128,2><<<GSEG, 256, 0, stream>>>(f2, sorted, offs, m2);
    reduce_level_kernel<64, 1><<<GSEG, 256, 0, stream>>>(f1, sorted, offs, m1);
    reduce_level_kernel<64, 0><<<GSEG, 256, 0, stream>>>(f0, sorted, offs, m0);

    gemm_ln_all_kernel<<<4*GSEG/GROWS, 256, 0, stream>>>(
        m0, m1, m2, m3,
        W0, b0, g0, bt0, W1, b1, g1, bt1,
        W2, b2, g2, bt2, W3, b3, g3, bt3, out);
}

// Round 6
// 215.193 us; speedup vs baseline: 1.1378x; 1.1310x over previous
//
#include <hip/hip_runtime.h>

#define N_PTS   524288
#define P_PTS   65536
#define B_SC    8
#define SEGS    512
#define GSEG    (B_SC*SEGS)      /* 4096 */
#define HID     256

typedef __attribute__((ext_vector_type(8))) short bf16x8;
typedef __attribute__((ext_vector_type(4))) float f32x4;

// Split fp32 into bf16 hi + bf16 lo (x ~= hi + lo; product error ~2^-16 rel)
__device__ __forceinline__ void bf16split(float x, unsigned short& h, unsigned short& l)
{
    const unsigned xi = __float_as_uint(x);
    const unsigned hi = (xi + 0x8000u) & 0xFFFF0000u;   // round-half-up to bf16
    const float hf = __uint_as_float(hi);
    const float r = x - hf;                              // exact (close values)
    const unsigned ri = (__float_as_uint(r) + 0x8000u) >> 16;
    h = (unsigned short)(hi >> 16);
    l = (unsigned short)(r == 0.f ? 0u : ri);
}

// ---------------------------------------------------------------------------
// Kernel 1: per-block partial histograms of p2s (no global atomics, no memset)
// ---------------------------------------------------------------------------
__global__ __launch_bounds__(256) void count_kernel(
    const int* __restrict__ p2s, int* __restrict__ part)
{
    __shared__ int lc[SEGS];
    const int t = threadIdx.x;
    lc[t] = 0; lc[t + 256] = 0;
    __syncthreads();
    const int q0 = blockIdx.x * 1024 + t * 4;
    const int4 s4 = *reinterpret_cast<const int4*>(p2s + q0);
    atomicAdd(&lc[s4.x], 1);
    atomicAdd(&lc[s4.y], 1);
    atomicAdd(&lc[s4.z], 1);
    atomicAdd(&lc[s4.w], 1);
    __syncthreads();
    part[blockIdx.x * SEGS + t]       = lc[t];
    part[blockIdx.x * SEGS + t + 256] = lc[t + 256];
}

// ---------------------------------------------------------------------------
// Kernel 2: sum partials -> per-seg counts -> exclusive scan (single block)
// ---------------------------------------------------------------------------
__global__ __launch_bounds__(1024) void scan_kernel(
    const int* __restrict__ part, int* __restrict__ offs, int* __restrict__ cursor)
{
    __shared__ int scnt[GSEG];     // 16 KB
    __shared__ int tmp[1024];
    const int t = threadIdx.x;
    const int k = t & 511;
    const int h = t >> 9;          // 0 or 1
    #pragma unroll
    for (int j = 0; j < 4; ++j) {
        const int scene = h + j * 2;
        const int* pp = part + (scene * 64) * SEGS + k;
        int s = 0;
        #pragma unroll 8
        for (int b = 0; b < 64; ++b) s += pp[b * SEGS];
        scnt[scene * SEGS + k] = s;
    }
    __syncthreads();

    int v[4]; int s = 0;
    #pragma unroll
    for (int i = 0; i < 4; ++i) { v[i] = scnt[t*4 + i]; s += v[i]; }
    tmp[t] = s;
    __syncthreads();
    for (int off = 1; off < 1024; off <<= 1) {
        int x = (t >= off) ? tmp[t - off] : 0;
        __syncthreads();
        tmp[t] += x;
        __syncthreads();
    }
    int excl = (t > 0) ? tmp[t-1] : 0;
    #pragma unroll
    for (int i = 0; i < 4; ++i) {
        offs[t*4 + i] = excl;
        cursor[t*4 + i] = excl;
        excl += v[i];
    }
    if (t == 1023) offs[4096] = excl;   // == N
}

// ---------------------------------------------------------------------------
// Kernel 3: fused compose + scatter into segment-contiguous sorted[]
// ---------------------------------------------------------------------------
__global__ __launch_bounds__(256) void build_kernel(
    const int* __restrict__ inv1, const int* __restrict__ inv2,
    const int* __restrict__ inv3, const int* __restrict__ p2s,
    int* __restrict__ cursor, int4* __restrict__ sorted)
{
    const int q0 = blockIdx.x * 1024 + threadIdx.x * 4;
    const int4 a4 = *reinterpret_cast<const int4*>(inv1 + q0);
    const int b0 = inv2[a4.x], b1 = inv2[a4.y], b2 = inv2[a4.z], b3 = inv2[a4.w];
    const int c0 = inv3[b0],   c1 = inv3[b1],   c2 = inv3[b2],   c3 = inv3[b3];
    const int4 s4 = *reinterpret_cast<const int4*>(p2s + q0);
    const int sbase = (q0 >> 16) * SEGS;
    const int p0 = atomicAdd(&cursor[sbase + s4.x], 1);
    const int p1 = atomicAdd(&cursor[sbase + s4.y], 1);
    const int p2 = atomicAdd(&cursor[sbase + s4.z], 1);
    const int p3 = atomicAdd(&cursor[sbase + s4.w], 1);
    sorted[p0] = make_int4(q0 + 0, a4.x, b0, c0);
    sorted[p1] = make_int4(q0 + 1, a4.y, b1, c1);
    sorted[p2] = make_int4(q0 + 2, a4.z, b2, c2);
    sorted[p3] = make_int4(q0 + 3, a4.w, b3, c3);
}

// ---------------------------------------------------------------------------
// Kernel 4 (x4 levels): per-segment mean of one level -> bf16 hi/lo pair.
// ---------------------------------------------------------------------------
template<int C, int SEL>
__global__ __launch_bounds__(256) void reduce_level_kernel(
    const float* __restrict__ fb, const int4* __restrict__ sorted,
    const int* __restrict__ offs,
    unsigned short* __restrict__ mh, unsigned short* __restrict__ ml)
{
    constexpr int CL = C / 4;        // float4 lanes per point
    constexpr int NS = 256 / CL;     // concurrent point slots
    __shared__ int    s_idx[512];
    __shared__ float4 s_red[256];

    const int g = blockIdx.x;
    const int start = offs[g], end = offs[g+1];
    const int t = threadIdx.x;
    const int slot = t / CL;
    const int coff = (t % CL) * 4;

    float ax = 0.f, ay = 0.f, az = 0.f, aw = 0.f;
    for (int cs = start; cs < end; cs += 512) {
        const int n = min(512, end - cs);
        __syncthreads();
        for (int i = t; i < n; i += 256) {
            const int4 v = sorted[cs + i];
            s_idx[i] = (SEL == 0) ? v.x : (SEL == 1) ? v.y : (SEL == 2) ? v.z : v.w;
        }
        __syncthreads();
        int k = slot;
        for (; k + 7*NS < n; k += 8*NS) {
            float4 v[8];
            #pragma unroll
            for (int u = 0; u < 8; ++u) {
                const int ia = s_idx[k + u*NS];
                v[u] = *reinterpret_cast<const float4*>(fb + (size_t)ia * C + coff);
            }
            #pragma unroll
            for (int u = 0; u < 8; ++u) {
                ax += v[u].x; ay += v[u].y; az += v[u].z; aw += v[u].w;
            }
        }
        for (; k < n; k += NS) {
            const int ia = s_idx[k];
            const float4 va = *reinterpret_cast<const float4*>(fb + (size_t)ia * C + coff);
            ax += va.x; ay += va.y; az += va.z; aw += va.w;
        }
    }

    s_red[t] = make_float4(ax, ay, az, aw);
    __syncthreads();
    if (t < CL) {
        float4 s = s_red[t];
        #pragma unroll
        for (int sl = 1; sl < NS; ++sl) {
            const float4 p = s_red[sl * CL + t];
            s.x += p.x; s.y += p.y; s.z += p.z; s.w += p.w;
        }
        const float inv = 1.0f / fmaxf((float)(end - start), 1.0f);
        s.x *= inv; s.y *= inv; s.z *= inv; s.w *= inv;
        ushort4 h4, l4;
        bf16split(s.x, h4.x, l4.x);
        bf16split(s.y, h4.y, l4.y);
        bf16split(s.z, h4.z, l4.z);
        bf16split(s.w, h4.w, l4.w);
        *reinterpret_cast<ushort4*>(mh + (size_t)g * C + t * 4) = h4;
        *reinterpret_cast<ushort4*>(ml + (size_t)g * C + t * 4) = l4;
    }
}

// ---------------------------------------------------------------------------
// Kernel 5: transpose W [C][256] -> Wt [256][C] as bf16 hi/lo (64x64 tiles)
// ---------------------------------------------------------------------------
__global__ __launch_bounds__(256) void convert_w_kernel(
    const float* __restrict__ W0, const float* __restrict__ W1,
    const float* __restrict__ W2, const float* __restrict__ W3,
    unsigned short* __restrict__ wth0, unsigned short* __restrict__ wtl0,
    unsigned short* __restrict__ wth1, unsigned short* __restrict__ wtl1,
    unsigned short* __restrict__ wth2, unsigned short* __restrict__ wtl2,
    unsigned short* __restrict__ wth3, unsigned short* __restrict__ wtl3)
{
    __shared__ float tile[64][65];
    const int blk = blockIdx.x;
    int lvl, ti;
    if (blk < 4)       { lvl = 0; ti = blk; }
    else if (blk < 8)  { lvl = 1; ti = blk - 4; }
    else if (blk < 16) { lvl = 2; ti = blk - 8; }
    else               { lvl = 3; ti = blk - 16; }
    const float* W; unsigned short *wh, *wl; int C;
    switch (lvl) {
        case 0:  W = W0; wh = wth0; wl = wtl0; C = 64;  break;
        case 1:  W = W1; wh = wth1; wl = wtl1; C = 64;  break;
        case 2:  W = W2; wh = wth2; wl = wtl2; C = 128; break;
        default: W = W3; wh = wth3; wl = wtl3; C = 256; break;
    }
    const int ktiles = C / 64;
    const int k0 = (ti % ktiles) * 64;
    const int c0 = (ti / ktiles) * 64;
    const int t = threadIdx.x, tw = t >> 6, tl = t & 63;
    #pragma unroll
    for (int i = 0; i < 16; ++i) {
        const int kr = tw * 16 + i;
        tile[kr][tl] = W[(size_t)(k0 + kr) * HID + c0 + tl];
    }
    __syncthreads();
    #pragma unroll
    for (int i = 0; i < 16; ++i) {
        const int cr = tw * 16 + i;
        const float x = tile[tl][cr];
        unsigned short h, l;
        bf16split(x, h, l);
        wh[(size_t)(c0 + cr) * C + k0 + tl] = h;
        wl[(size_t)(c0 + cr) * C + k0 + tl] = l;
    }
}

// ---------------------------------------------------------------------------
// Kernel 6: MFMA GEMM (bf16 hi/lo x3 passes = ~fp32) + bias + LayerNorm.
// Block = 64 rows x 256 cols, 4 waves; wave w owns rows [w*16, w*16+16).
// A frags in registers for full K; 16 col-tiles sequential, acc -> LDS -> LN.
// ---------------------------------------------------------------------------
template<int C>
__device__ __forceinline__ void gemm_ln_mfma_body(
    float* sh, int row0,
    const unsigned short* __restrict__ mh, const unsigned short* __restrict__ ml,
    const unsigned short* __restrict__ wth, const unsigned short* __restrict__ wtl,
    const float* __restrict__ bias, const float* __restrict__ gma,
    const float* __restrict__ bta, float* __restrict__ out)
{
    constexpr int KS = C / 32;
    const int t = threadIdx.x;
    const int w = t >> 6, l = t & 63;
    const int arow = row0 + w * 16 + (l & 15);
    const int kgrp = (l >> 4) * 8;

    bf16x8 Ah[KS], Al[KS];
    #pragma unroll
    for (int s = 0; s < KS; ++s) {
        Ah[s] = *reinterpret_cast<const bf16x8*>(mh + (size_t)arow * C + s * 32 + kgrp);
        Al[s] = *reinterpret_cast<const bf16x8*>(ml + (size_t)arow * C + s * 32 + kgrp);
    }

    #pragma unroll
    for (int ct = 0; ct < 16; ++ct) {
        const int bcol = ct * 16 + (l & 15);
        f32x4 acc = {0.f, 0.f, 0.f, 0.f};
        #pragma unroll
        for (int s = 0; s < KS; ++s) {
            const bf16x8 Bh = *reinterpret_cast<const bf16x8*>(wth + (size_t)bcol * C + s * 32 + kgrp);
            const bf16x8 Bl = *reinterpret_cast<const bf16x8*>(wtl + (size_t)bcol * C + s * 32 + kgrp);
            acc = __builtin_amdgcn_mfma_f32_16x16x32_bf16(Al[s], Bh, acc, 0, 0, 0);
            acc = __builtin_amdgcn_mfma_f32_16x16x32_bf16(Ah[s], Bl, acc, 0, 0, 0);
            acc = __builtin_amdgcn_mfma_f32_16x16x32_bf16(Ah[s], Bh, acc, 0, 0, 0);
        }
        const int lrow = w * 16 + (l >> 4) * 4;
        const int lcol = ct * 16 + (l & 15);
        #pragma unroll
        for (int v = 0; v < 4; ++v) sh[(lrow + v) * HID + lcol] = acc[v];
    }
    __syncthreads();

    // LayerNorm: wave w handles the 16 rows it computed
    const int lane = l;
    const float b0 = bias[lane], b1 = bias[lane + 64], b2 = bias[lane + 128], b3 = bias[lane + 192];
    const float g0 = gma[lane],  g1 = gma[lane + 64],  g2 = gma[lane + 128],  g3 = gma[lane + 192];
    const float t0 = bta[lane],  t1 = bta[lane + 64],  t2 = bta[lane + 128],  t3 = bta[lane + 192];
    for (int r = w * 16; r < w * 16 + 16; ++r) {
        const float* row = sh + r * HID;
        const float v0 = row[lane      ] + b0;
        const float v1 = row[lane + 64 ] + b1;
        const float v2 = row[lane + 128] + b2;
        const float v3 = row[lane + 192] + b3;
        float s  = v0 + v1 + v2 + v3;
        float sq = v0*v0 + v1*v1 + v2*v2 + v3*v3;
        #pragma unroll
        for (int o = 32; o > 0; o >>= 1) {
            s  += __shfl_xor(s,  o);
            sq += __shfl_xor(sq, o);
        }
        const float mean = s * (1.0f / 256.0f);
        const float var  = sq * (1.0f / 256.0f) - mean * mean;
        const float rs   = rsqrtf(var + 1e-5f);
        float* o_ = out + ((size_t)(row0 + r)) * HID;
        o_[lane      ] = (v0 - mean) * rs * g0 + t0;
        o_[lane + 64 ] = (v1 - mean) * rs * g1 + t1;
        o_[lane + 128] = (v2 - mean) * rs * g2 + t2;
        o_[lane + 192] = (v3 - mean) * rs * g3 + t3;
    }
}

__global__ __launch_bounds__(256) void gemm_ln_mfma_kernel(
    const unsigned short* __restrict__ mh0, const unsigned short* __restrict__ ml0,
    const unsigned short* __restrict__ mh1, const unsigned short* __restrict__ ml1,
    const unsigned short* __restrict__ mh2, const unsigned short* __restrict__ ml2,
    const unsigned short* __restrict__ mh3, const unsigned short* __restrict__ ml3,
    const unsigned short* __restrict__ wth0, const unsigned short* __restrict__ wtl0,
    const unsigned short* __restrict__ wth1, const unsigned short* __restrict__ wtl1,
    const unsigned short* __restrict__ wth2, const unsigned short* __restrict__ wtl2,
    const unsigned short* __restrict__ wth3, const unsigned short* __restrict__ wtl3,
    const float* __restrict__ b0, const float* __restrict__ g0, const float* __restrict__ bt0,
    const float* __restrict__ b1, const float* __restrict__ g1, const float* __restrict__ bt1,
    const float* __restrict__ b2, const float* __restrict__ g2, const float* __restrict__ bt2,
    const float* __restrict__ b3, const float* __restrict__ g3, const float* __restrict__ bt3,
    float* __restrict__ out)
{
    __shared__ float sh[64 * HID];              // 64 KB
    const int blk = blockIdx.x;
    const int level = blk & 3;                  // interleave levels across CUs
    const int row0 = (blk >> 2) * 64;
    const size_t slab = (size_t)GSEG * HID;
    switch (level) {
        case 0: gemm_ln_mfma_body<64 >(sh, row0, mh0, ml0, wth0, wtl0, b0, g0, bt0, out + 3*slab); break;
        case 1: gemm_ln_mfma_body<64 >(sh, row0, mh1, ml1, wth1, wtl1, b1, g1, bt1, out + 2*slab); break;
        case 2: gemm_ln_mfma_body<128>(sh, row0, mh2, ml2, wth2, wtl2, b2, g2, bt2, out + 1*slab); break;
        default: gemm_ln_mfma_body<256>(sh, row0, mh3, ml3, wth3, wtl3, b3, g3, bt3, out); break;
    }
}

// ---------------------------------------------------------------------------
extern "C" void kernel_launch(void* const* d_in, const int* in_sizes, int n_in,
                              void* d_out, int out_size, void* d_ws, size_t ws_size,
                              hipStream_t stream)
{
    const float* f0  = (const float*)d_in[0];
    const float* f1  = (const float*)d_in[1];
    const float* f2  = (const float*)d_in[2];
    const float* f3  = (const float*)d_in[3];
    const int* inv1  = (const int*)d_in[4];
    const int* inv2  = (const int*)d_in[5];
    const int* inv3  = (const int*)d_in[6];
    const int* p2s   = (const int*)d_in[7];
    const float* W0  = (const float*)d_in[8];
    const float* b0  = (const float*)d_in[9];
    const float* g0  = (const float*)d_in[10];
    const float* bt0 = (const float*)d_in[11];
    const float* W1  = (const float*)d_in[12];
    const float* b1  = (const float*)d_in[13];
    const float* g1  = (const float*)d_in[14];
    const float* bt1 = (const float*)d_in[15];
    const float* W2  = (const float*)d_in[16];
    const float* b2  = (const float*)d_in[17];
    const float* g2  = (const float*)d_in[18];
    const float* bt2 = (const float*)d_in[19];
    const float* W3  = (const float*)d_in[20];
    const float* b3  = (const float*)d_in[21];
    const float* g3  = (const float*)d_in[22];
    const float* bt3 = (const float*)d_in[23];
    float* out = (float*)d_out;

    char* ws = (char*)d_ws;
    int4*  sorted = (int4*)(ws);                           // 8 MB
    int*   part   = (int*)(ws + (8u<<20));                 // 1 MB
    int*   offs   = (int*)(ws + (9u<<20));                 // 16.4 KB
    int*   cursor = (int*)(ws + (9u<<20) + 32768);         // 16 KB
    unsigned short* mh0 = (unsigned short*)(ws + (10u<<20));        // 512 KB
    unsigned short* mh1 = mh0 + (size_t)GSEG * 64;                  // 512 KB
    unsigned short* mh2 = mh1 + (size_t)GSEG * 64;                  // 1 MB
    unsigned short* mh3 = mh2 + (size_t)GSEG * 128;                 // 2 MB
    unsigned short* ml0 = (unsigned short*)(ws + (14u<<20));
    unsigned short* ml1 = ml0 + (size_t)GSEG * 64;
    unsigned short* ml2 = ml1 + (size_t)GSEG * 64;
    unsigned short* ml3 = ml2 + (size_t)GSEG * 128;
    unsigned short* wth0 = (unsigned short*)(ws + (18u<<20));       // 32 KB
    unsigned short* wth1 = wth0 + 64  * HID;
    unsigned short* wth2 = wth1 + 64  * HID;
    unsigned short* wth3 = wth2 + 128 * HID;
    unsigned short* wtl0 = (unsigned short*)(ws + (18u<<20) + (512u<<10));
    unsigned short* wtl1 = wtl0 + 64  * HID;
    unsigned short* wtl2 = wtl1 + 64  * HID;
    unsigned short* wtl3 = wtl2 + 128 * HID;

    count_kernel<<<N_PTS/1024, 256, 0, stream>>>(p2s, part);
    scan_kernel<<<1, 1024, 0, stream>>>(part, offs, cursor);
    build_kernel<<<N_PTS/1024, 256, 0, stream>>>(inv1, inv2, inv3, p2s, cursor, sorted);
    convert_w_kernel<<<32, 256, 0, stream>>>(W0, W1, W2, W3,
        wth0, wtl0, wth1, wtl1, wth2, wtl2, wth3, wtl3);

    reduce_level_kernel<256,3><<<GSEG, 256, 0, stream>>>(f3, sorted, offs, mh3, ml3);
    reduce_level_kernel<128,2><<<GSEG, 256, 0, stream>>>(f2, sorted, offs, mh2, ml2);
    reduce_level_kernel<64, 1><<<GSEG, 256, 0, stream>>>(f1, sorted, offs, mh1, ml1);
    reduce_level_kernel<64, 0><<<GSEG, 256, 0, stream>>>(f0, sorted, offs, mh0, ml0);

    gemm_ln_mfma_kernel<<<4*GSEG/64, 256, 0, stream>>>(
        mh0, ml0, mh1, ml1, mh2, ml2, mh3, ml3,
        wth0, wtl0, wth1, wtl1, wth2, wtl2, wth3, wtl3,
        b0, g0, bt0, b1, g1, bt1, b2, g2, bt2, b3, g3, bt3, out);
}